// Round 8
// baseline (973.067 us; speedup 1.0000x reference)
//
#include <hip/hip_runtime.h>
#include <hip/hip_bf16.h>
#include <math.h>

#define BSZ   1024
#define TLEN  320
#define EEGC  64
#define GEOC  18
#define ECH   512    // 64*8
#define GCH   144    // 18*8
#define HID   32
#define KW    32
#define TT    32
#define NT    (TLEN/TT)   // 10

// ---- workspace layout (float offsets) ----
#define OFF_ENC  0
#define OFF_MOD  (OFF_ENC + BSZ*TLEN*HID)
#define OFF_DP   (OFF_MOD + BSZ*TLEN*HID)
#define OFF_CWE  (OFF_DP + BSZ*HID*10)           // conv weights eeg [c][k] (A1-folded)
#define OFF_CWG  (OFF_CWE + ECH*KW)
#define OFF_DWE  (OFF_CWG + GCH*KW)              // dense weights eeg [c][h] (A2-folded)
#define OFF_DWG  (OFF_DWE + ECH*HID)
#define OFF_BTE  (OFF_DWG + GCH*HID)
#define OFF_BTG  (OFF_BTE + HID)
#define OFF_GAM  (OFF_BTG + HID)

struct P29 { const float* p[29]; };
// 0 ecw 1 ecb 2 e1s 3 e1b 4 e1m 5 e1v 6 edw 7 edb 8 e2s 9 e2b 10 e2m 11 e2v
// 12 gcw 13 gcb 14 g1s 15 g1b 16 g1m 17 g1v 18 gdw 19 gdb 20 g2s 21 g2b 22 g2m 23 g2v
// 24 gamma 25 fc1w 26 fc1b 27 fc2w 28 fc2b

// ============================================================
// prep: fold BN1 into conv weights, BN2 into dense weights, biases
// into one per-h bias; stash gamma.
// ============================================================
__global__ __launch_bounds__(256) void prep_kernel(P29 P, float* __restrict__ ws)
{
    const int tid = threadIdx.x;
    float* convW_e = ws + OFF_CWE;
    float* convW_g = ws + OFF_CWG;
    float* dW_e    = ws + OFF_DWE;
    float* dW_g    = ws + OFF_DWG;

    for (int i = tid; i < ECH * KW; i += 256) {
        int c = i >> 5, k = i & 31;
        float A1 = P.p[2][c] * rsqrtf(P.p[5][c] + 1e-5f);
        convW_e[c * KW + k] = P.p[0][(size_t)k * ECH + c] * A1;
    }
    for (int i = tid; i < GCH * KW; i += 256) {
        int c = i >> 5, k = i & 31;
        float A1 = P.p[14][c] * rsqrtf(P.p[17][c] + 1e-5f);
        convW_g[c * KW + k] = P.p[12][(size_t)k * GCH + c] * A1;
    }
    for (int i = tid; i < ECH * HID; i += 256) {
        int h = i & 31;
        float A2 = P.p[8][h] * rsqrtf(P.p[11][h] + 1e-5f);
        dW_e[i] = P.p[6][i] * A2;
    }
    for (int i = tid; i < GCH * HID; i += 256) {
        int h = i & 31;
        float A2 = P.p[20][h] * rsqrtf(P.p[23][h] + 1e-5f);
        dW_g[i] = P.p[18][i] * A2;
    }
    for (int i = tid; i < HID; i += 256) ws[OFF_GAM + i] = P.p[24][i];

    if (tid < HID) {
        int h = tid;
        float A2 = P.p[8][h] * rsqrtf(P.p[11][h] + 1e-5f);
        float s = 0.f;
        for (int c = 0; c < ECH; ++c) {
            float A1 = P.p[2][c] * rsqrtf(P.p[5][c] + 1e-5f);
            float C1 = (P.p[1][c] - P.p[4][c]) * A1 + P.p[3][c];
            s += C1 * P.p[6][(size_t)c * HID + h];
        }
        ws[OFF_BTE + h] = A2 * (s + P.p[7][h] - P.p[10][h]) + P.p[9][h];
    } else if (tid >= 64 && tid < 64 + HID) {
        int h = tid - 64;
        float A2 = P.p[20][h] * rsqrtf(P.p[23][h] + 1e-5f);
        float s = 0.f;
        for (int c = 0; c < GCH; ++c) {
            float A1 = P.p[14][c] * rsqrtf(P.p[17][c] + 1e-5f);
            float C1 = (P.p[13][c] - P.p[16][c]) * A1 + P.p[15][c];
            s += C1 * P.p[18][(size_t)c * HID + h];
        }
        ws[OFF_BTG + h] = A2 * (s + P.p[19][h] - P.p[22][h]) + P.p[21][h];
    }
}

// conv inner: stream 12 b128 chunks of the 47-wide window with 1-deep
// lookahead; per-t FMA order is j (=t+k) ascending == k ascending:
// bit-identical to the scalar version.
__device__ __forceinline__ void conv_stream(const float4* __restrict__ xp4,
                                            const float* __restrict__ w,
                                            float* __restrict__ acc)
{
    float4 cur = xp4[0];
    #pragma unroll
    for (int j4 = 0; j4 < 12; ++j4) {
        float4 nxt = (j4 < 11) ? xp4[j4 + 1] : cur;
        #pragma unroll
        for (int i2 = 0; i2 < 4; ++i2) {
            const int i = j4 * 4 + i2;
            const float xv = (i2 == 0) ? cur.x : (i2 == 1) ? cur.y
                           : (i2 == 2) ? cur.z : cur.w;
            const int tlo = (i - 31 > 0) ? (i - 31) : 0;
            const int thi = (i < 15) ? i : 15;
            #pragma unroll
            for (int t = tlo; t <= thi; ++t)
                acc[t] = fmaf(xv, w[i - t], acc[t]);
        }
        cur = nxt;
    }
}

// ============================================================
// EEG path. Grid (NT, BSZ), block 256. 4 phases of 128 channels.
// xsT transposed [ch][j] stride 68 -> conv window via ds_read_b128 stream.
// dense: 4t x 4h, q = wave (4 chunks of 32 c/phase), 1-deep prefetch,
// stash-reduce at end. LDS = 4352 + 5120 fl = 37 KB -> 4 blocks/CU.
// waves_per_eu(4,4): pin scheduler to the LDS-capped occupancy so the
// allocator spends VGPRs on ILP (r7's 64-reg schedule was latency-bound).
// ============================================================
__global__ __launch_bounds__(256, 4)
__attribute__((amdgpu_waves_per_eu(4, 4)))
void path_eeg(const float* __restrict__ x, float* __restrict__ ws)
{
    __shared__ __align__(16) float xsT[EEGC * 68];  // [ch][j], 17408 B
    __shared__ __align__(16) float czs[5120];       // cz[128*36] / stash[256*20]

    const int b   = blockIdx.y;
    const int t0  = blockIdx.x * TT;
    const int tid = threadIdx.x;
    const float* convW = ws + OFF_CWE;
    const float* dW    = ws + OFF_DWE;
    float* enc         = ws + OFF_ENC;
    float* cz          = czs;

    // stage x window transposed (zero-padded), coalesced global reads
    const float* xb = x + (size_t)b * (TLEN * EEGC);
    for (int i = tid; i < 63 * EEGC; i += 256) {
        int j = i >> 6, ch = i & 63;
        int t = t0 - 15 + j;
        xsT[ch * 68 + j] = (t >= 0 && t < TLEN) ? xb[(size_t)t * EEGC + ch] : 0.f;
    }
    __syncthreads();

    const int tg = tid & 7, hg = (tid >> 3) & 7, q = tid >> 6;
    const int c_loc = tid & 127, th = tid >> 7;
    float a00=0,a01=0,a02=0,a03=0, a10=0,a11=0,a12=0,a13=0;
    float a20=0,a21=0,a22=0,a23=0, a30=0,a31=0,a32=0,a33=0;

    #pragma unroll 1
    for (int ph = 0; ph < 4; ++ph) {
        if (ph) __syncthreads();   // previous dense reads done before cz overwrite
        // ---- conv: channel c = ph*128 + c_loc, t's [th*16, th*16+16) ----
        {
            const int c  = ph * 128 + c_loc;
            const int ch = c >> 3;
            float w[KW];
            const float4* wp4 = (const float4*)(convW + c * KW);
            #pragma unroll
            for (int k4 = 0; k4 < 8; ++k4) {
                float4 v = wp4[k4];
                w[4*k4+0]=v.x; w[4*k4+1]=v.y; w[4*k4+2]=v.z; w[4*k4+3]=v.w;
            }
            float acc[16];
            #pragma unroll
            for (int t = 0; t < 16; ++t) acc[t] = 0.f;
            conv_stream((const float4*)(xsT + ch * 68 + th * 16), w, acc);
            float4* czp = (float4*)(cz + c_loc * 36 + th * 16);
            czp[0] = make_float4(acc[0],  acc[1],  acc[2],  acc[3]);
            czp[1] = make_float4(acc[4],  acc[5],  acc[6],  acc[7]);
            czp[2] = make_float4(acc[8],  acc[9],  acc[10], acc[11]);
            czp[3] = make_float4(acc[12], acc[13], acc[14], acc[15]);
        }
        __syncthreads();
        // ---- dense partial: my wave's 32-c chunk, 1-deep prefetch ----
        {
            const float* dWh = dW + (size_t)(ph * 128 + q * 32) * HID + hg * 4;
            const float* czb = cz + (q * 32) * 36 + tg * 4;
            float4 cv = *(const float4*)(czb);
            float4 wv = *(const float4*)(dWh);
            #pragma unroll
            for (int ci = 0; ci < 32; ++ci) {
                float4 cvn, wvn;
                if (ci < 31) {
                    cvn = *(const float4*)(czb + (ci + 1) * 36);
                    wvn = *(const float4*)(dWh + (ci + 1) * HID);
                } else { cvn = cv; wvn = wv; }
                a00 = fmaf(cv.x, wv.x, a00); a01 = fmaf(cv.x, wv.y, a01);
                a02 = fmaf(cv.x, wv.z, a02); a03 = fmaf(cv.x, wv.w, a03);
                a10 = fmaf(cv.y, wv.x, a10); a11 = fmaf(cv.y, wv.y, a11);
                a12 = fmaf(cv.y, wv.z, a12); a13 = fmaf(cv.y, wv.w, a13);
                a20 = fmaf(cv.z, wv.x, a20); a21 = fmaf(cv.z, wv.y, a21);
                a22 = fmaf(cv.z, wv.z, a22); a23 = fmaf(cv.z, wv.w, a23);
                a30 = fmaf(cv.w, wv.x, a30); a31 = fmaf(cv.w, wv.y, a31);
                a32 = fmaf(cv.w, wv.z, a32); a33 = fmaf(cv.w, wv.w, a33);
                cv = cvn; wv = wvn;
            }
        }
    }

    // ---- 4-chunk reduction via LDS (stash stride 20, b128) ----
    __syncthreads();
    float* stash = czs;   // 256*20 = 5120 floats
    {
        float4* sp = (float4*)(stash + tid * 20);
        sp[0] = make_float4(a00,a01,a02,a03);
        sp[1] = make_float4(a10,a11,a12,a13);
        sp[2] = make_float4(a20,a21,a22,a23);
        sp[3] = make_float4(a30,a31,a32,a33);
    }
    __syncthreads();
    {
        const int t = tid >> 3, hq = tid & 7;
        float4 v = make_float4(0.f,0.f,0.f,0.f);
        #pragma unroll
        for (int qq = 0; qq < 4; ++qq) {
            const int partner = qq * 64 + hq * 8 + (t >> 2);
            float4 s = *(const float4*)(stash + partner * 20 + (t & 3) * 4);
            v.x += s.x; v.y += s.y; v.z += s.z; v.w += s.w;
        }
        float4 bias = *(const float4*)(ws + OFF_BTE + hq * 4);
        v.x = fmaxf(v.x + bias.x, 0.f);
        v.y = fmaxf(v.y + bias.y, 0.f);
        v.z = fmaxf(v.z + bias.z, 0.f);
        v.w = fmaxf(v.w + bias.w, 0.f);
        *(float4*)(enc + ((size_t)(b * TLEN + t0 + t)) * HID + hq * 4) = v;
    }
}

// ============================================================
// GEO path: 144 channels, xsT-staged streamed conv (tid<144, both th),
// dense 4 chunks of 36 c with prefetch, sigmoid.
// LDS = 1224 + 5184 floats = 25.6 KB -> 6 blocks/CU; waves_per_eu(6,6).
// ============================================================
__global__ __launch_bounds__(256, 6)
__attribute__((amdgpu_waves_per_eu(6, 6)))
void path_geo(const float* __restrict__ x, float* __restrict__ ws)
{
    __shared__ __align__(16) float xsT[GEOC * 68];  // 1224 floats
    __shared__ __align__(16) float cz[GCH * 36];    // 5184 floats (stash 5120 fits)

    const int b   = blockIdx.y;
    const int t0  = blockIdx.x * TT;
    const int tid = threadIdx.x;
    const float* convW = ws + OFF_CWG;
    const float* dW    = ws + OFF_DWG;
    float* mod         = ws + OFF_MOD;

    const float* xb = x + (size_t)b * (TLEN * GEOC);
    for (int i = tid; i < 63 * GEOC; i += 256) {
        int j = i / GEOC, ch = i - j * GEOC;
        int t = t0 - 15 + j;
        xsT[ch * 68 + j] = (t >= 0 && t < TLEN) ? xb[(size_t)t * GEOC + ch] : 0.f;
    }
    __syncthreads();

    if (tid < GCH) {
        const int c  = tid;
        const int ch = c >> 3;
        float w[KW];
        const float4* wp4 = (const float4*)(convW + c * KW);
        #pragma unroll
        for (int k4 = 0; k4 < 8; ++k4) {
            float4 v = wp4[k4];
            w[4*k4+0]=v.x; w[4*k4+1]=v.y; w[4*k4+2]=v.z; w[4*k4+3]=v.w;
        }
        #pragma unroll 1
        for (int th = 0; th < 2; ++th) {
            float acc[16];
            #pragma unroll
            for (int t = 0; t < 16; ++t) acc[t] = 0.f;
            conv_stream((const float4*)(xsT + ch * 68 + th * 16), w, acc);
            float4* czp = (float4*)(cz + tid * 36 + th * 16);
            czp[0] = make_float4(acc[0],  acc[1],  acc[2],  acc[3]);
            czp[1] = make_float4(acc[4],  acc[5],  acc[6],  acc[7]);
            czp[2] = make_float4(acc[8],  acc[9],  acc[10], acc[11]);
            czp[3] = make_float4(acc[12], acc[13], acc[14], acc[15]);
        }
    }
    __syncthreads();

    const int tg = tid & 7, hg = (tid >> 3) & 7, q = tid >> 6;
    float a00=0,a01=0,a02=0,a03=0, a10=0,a11=0,a12=0,a13=0;
    float a20=0,a21=0,a22=0,a23=0, a30=0,a31=0,a32=0,a33=0;
    {
        const float* dWh = dW + (size_t)(q * 36) * HID + hg * 4;
        const float* czb = cz + (q * 36) * 36 + tg * 4;
        float4 cv = *(const float4*)(czb);
        float4 wv = *(const float4*)(dWh);
        #pragma unroll
        for (int ci = 0; ci < 36; ++ci) {
            float4 cvn, wvn;
            if (ci < 35) {
                cvn = *(const float4*)(czb + (ci + 1) * 36);
                wvn = *(const float4*)(dWh + (ci + 1) * HID);
            } else { cvn = cv; wvn = wv; }
            a00 = fmaf(cv.x, wv.x, a00); a01 = fmaf(cv.x, wv.y, a01);
            a02 = fmaf(cv.x, wv.z, a02); a03 = fmaf(cv.x, wv.w, a03);
            a10 = fmaf(cv.y, wv.x, a10); a11 = fmaf(cv.y, wv.y, a11);
            a12 = fmaf(cv.y, wv.z, a12); a13 = fmaf(cv.y, wv.w, a13);
            a20 = fmaf(cv.z, wv.x, a20); a21 = fmaf(cv.z, wv.y, a21);
            a22 = fmaf(cv.z, wv.z, a22); a23 = fmaf(cv.z, wv.w, a23);
            a30 = fmaf(cv.w, wv.x, a30); a31 = fmaf(cv.w, wv.y, a31);
            a32 = fmaf(cv.w, wv.z, a32); a33 = fmaf(cv.w, wv.w, a33);
            cv = cvn; wv = wvn;
        }
    }
    __syncthreads();
    float* stash = cz;
    {
        float4* sp = (float4*)(stash + tid * 20);
        sp[0] = make_float4(a00,a01,a02,a03);
        sp[1] = make_float4(a10,a11,a12,a13);
        sp[2] = make_float4(a20,a21,a22,a23);
        sp[3] = make_float4(a30,a31,a32,a33);
    }
    __syncthreads();
    {
        const int t = tid >> 3, hq = tid & 7;
        float4 v = make_float4(0.f,0.f,0.f,0.f);
        #pragma unroll
        for (int qq = 0; qq < 4; ++qq) {
            const int partner = qq * 64 + hq * 8 + (t >> 2);
            float4 s = *(const float4*)(stash + partner * 20 + (t & 3) * 4);
            v.x += s.x; v.y += s.y; v.z += s.z; v.w += s.w;
        }
        float4 bias = *(const float4*)(ws + OFF_BTG + hq * 4);
        v.x = 1.f / (1.f + expf(-(v.x + bias.x)));
        v.y = 1.f / (1.f + expf(-(v.y + bias.y)));
        v.z = 1.f / (1.f + expf(-(v.z + bias.z)));
        v.w = 1.f / (1.f + expf(-(v.w + bias.w)));
        *(float4*)(mod + ((size_t)(b * TLEN + t0 + t)) * HID + hq * 4) = v;
    }
}

// ============================================================
// SNN scan: one thread per (b,h). 320 serial steps; windowed mean-diff
// fused in-register. dp[b][h*10+w]
// ============================================================
__global__ __launch_bounds__(256) void scan_kernel(float* __restrict__ ws)
{
    const int idx = blockIdx.x * 256 + threadIdx.x;   // 0..32767
    const int b = idx >> 5, h = idx & 31;
    const float g = ws[OFF_GAM + h];
    const float* pe = ws + OFF_ENC + (size_t)b * TLEN * HID + h;
    const float* pg = ws + OFF_MOD + (size_t)b * TLEN * HID + h;
    float m1 = 0.f, m2 = 0.f, m3 = 0.f, ma = 0.f, eta = 0.f, mli = 0.f, prev = 0.f;
    float acc_lo = 0.f, acc_hi = 0.f;
    float* dpp = ws + OFF_DP + b * (HID * 10) + h * 10;
    int w = 0;
    #pragma unroll 8
    for (int t = 0; t < TLEN; ++t) {
        const float ce = pe[t * HID];
        const float cg = pg[t * HID];
        m1 = 0.9f * m1 + ce; float s1 = ((m1 - 0.7f) >= 0.f) ? 1.f : 0.f; m1 = m1 * (1.f - s1);
        m2 = 0.8f * m2 + ce; float s2 = ((m2 - 0.5f) >= 0.f) ? 1.f : 0.f; m2 = m2 * (1.f - s2);
        m3 = 0.6f * m3 + ce; float s3 = ((m3 - 0.3f) >= 0.f) ? 1.f : 0.f; m3 = m3 * (1.f - s3);
        const float hr = (s1 + s2 + s3) / 3.0f;
        eta = 0.36f * eta + 0.64f * prev;
        const float theta = 0.5f + 1.8f * eta - g * cg;
        ma = 0.8f * ma + hr;
        const float sa = ((ma - theta) >= 0.f) ? 1.f : 0.f;
        ma = ma * (1.f - sa);
        mli = 0.9f * mli + sa;
        prev = sa;
        if ((t & 31) < 16) acc_lo += mli; else acc_hi += mli;
        if ((t & 31) == 31) {
            dpp[w] = acc_hi * (1.f / 16.f) - acc_lo * (1.f / 16.f);
            acc_lo = 0.f; acc_hi = 0.f; ++w;
        }
    }
}

// ============================================================
// Head: fc1 (320->128) + ELU + fc2 (128->4). One block per b. f32 out.
// ============================================================
__global__ __launch_bounds__(128) void head_kernel(
    const float* __restrict__ ws,
    const float* __restrict__ f1w, const float* __restrict__ f1b,
    const float* __restrict__ f2w, const float* __restrict__ f2b,
    float* __restrict__ out)
{
    __shared__ float act[128];
    const int b = blockIdx.x, j = threadIdx.x;
    const float* dpb = ws + OFF_DP + b * 320;
    float a = f1b[j];
    for (int i = 0; i < 320; ++i)
        a = fmaf(dpb[i], f1w[i * 128 + j], a);
    act[j] = (a > 0.f) ? a : expm1f(a);   // ELU, alpha=1
    __syncthreads();
    if (j < 4) {
        float o = f2b[j];
        for (int jj = 0; jj < 128; ++jj)
            o = fmaf(act[jj], f2w[jj * 4 + j], o);
        out[b * 4 + j] = o;
    }
}

// ============================================================
extern "C" void kernel_launch(void* const* d_in, const int* in_sizes, int n_in,
                              void* d_out, int out_size, void* d_ws, size_t ws_size,
                              hipStream_t stream)
{
    float* ws = (float*)d_ws;

    P29 P;
    for (int k = 0; k < 29; ++k) P.p[k] = (const float*)d_in[k + 2];
    prep_kernel<<<1, 256, 0, stream>>>(P, ws);

    path_eeg<<<dim3(NT, BSZ), 256, 0, stream>>>((const float*)d_in[0], ws);
    path_geo<<<dim3(NT, BSZ), 256, 0, stream>>>((const float*)d_in[1], ws);

    scan_kernel<<<(BSZ * HID) / 256, 256, 0, stream>>>(ws);

    head_kernel<<<BSZ, 128, 0, stream>>>(
        ws, (const float*)d_in[27], (const float*)d_in[28],
        (const float*)d_in[29], (const float*)d_in[30], (float*)d_out);
}

// Round 9
// 872.715 us; speedup vs baseline: 1.1150x; 1.1150x over previous
//
#include <hip/hip_runtime.h>
#include <hip/hip_bf16.h>
#include <math.h>

#define BSZ   1024
#define TLEN  320
#define EEGC  64
#define GEOC  18
#define ECH   512    // 64*8
#define GCH   144    // 18*8
#define HID   32
#define KW    32
#define TT    32
#define NT    (TLEN/TT)   // 10

// ---- workspace layout (float offsets) ----
#define OFF_ENC  0
#define OFF_MOD  (OFF_ENC + BSZ*TLEN*HID)
#define OFF_DP   (OFF_MOD + BSZ*TLEN*HID)
#define OFF_CWE  (OFF_DP + BSZ*HID*10)           // conv weights eeg [c][k] (A1-folded)
#define OFF_CWG  (OFF_CWE + ECH*KW)
#define OFF_DWE  (OFF_CWG + GCH*KW)              // dense weights eeg [c][h] (A2-folded)
#define OFF_DWG  (OFF_DWE + ECH*HID)
#define OFF_BTE  (OFF_DWG + GCH*HID)
#define OFF_BTG  (OFF_BTE + HID)
#define OFF_GAM  (OFF_BTG + HID)

struct P29 { const float* p[29]; };
// 0 ecw 1 ecb 2 e1s 3 e1b 4 e1m 5 e1v 6 edw 7 edb 8 e2s 9 e2b 10 e2m 11 e2v
// 12 gcw 13 gcb 14 g1s 15 g1b 16 g1m 17 g1v 18 gdw 19 gdb 20 g2s 21 g2b 22 g2m 23 g2v
// 24 gamma 25 fc1w 26 fc1b 27 fc2w 28 fc2b

// ============================================================
// prep: fold BN1 into conv weights, BN2 into dense weights, biases
// into one per-h bias; stash gamma.
// ============================================================
__global__ __launch_bounds__(256) void prep_kernel(P29 P, float* __restrict__ ws)
{
    const int tid = threadIdx.x;
    float* convW_e = ws + OFF_CWE;
    float* convW_g = ws + OFF_CWG;
    float* dW_e    = ws + OFF_DWE;
    float* dW_g    = ws + OFF_DWG;

    for (int i = tid; i < ECH * KW; i += 256) {
        int c = i >> 5, k = i & 31;
        float A1 = P.p[2][c] * rsqrtf(P.p[5][c] + 1e-5f);
        convW_e[c * KW + k] = P.p[0][(size_t)k * ECH + c] * A1;
    }
    for (int i = tid; i < GCH * KW; i += 256) {
        int c = i >> 5, k = i & 31;
        float A1 = P.p[14][c] * rsqrtf(P.p[17][c] + 1e-5f);
        convW_g[c * KW + k] = P.p[12][(size_t)k * GCH + c] * A1;
    }
    for (int i = tid; i < ECH * HID; i += 256) {
        int h = i & 31;
        float A2 = P.p[8][h] * rsqrtf(P.p[11][h] + 1e-5f);
        dW_e[i] = P.p[6][i] * A2;
    }
    for (int i = tid; i < GCH * HID; i += 256) {
        int h = i & 31;
        float A2 = P.p[20][h] * rsqrtf(P.p[23][h] + 1e-5f);
        dW_g[i] = P.p[18][i] * A2;
    }
    for (int i = tid; i < HID; i += 256) ws[OFF_GAM + i] = P.p[24][i];

    if (tid < HID) {
        int h = tid;
        float A2 = P.p[8][h] * rsqrtf(P.p[11][h] + 1e-5f);
        float s = 0.f;
        for (int c = 0; c < ECH; ++c) {
            float A1 = P.p[2][c] * rsqrtf(P.p[5][c] + 1e-5f);
            float C1 = (P.p[1][c] - P.p[4][c]) * A1 + P.p[3][c];
            s += C1 * P.p[6][(size_t)c * HID + h];
        }
        ws[OFF_BTE + h] = A2 * (s + P.p[7][h] - P.p[10][h]) + P.p[9][h];
    } else if (tid >= 64 && tid < 64 + HID) {
        int h = tid - 64;
        float A2 = P.p[20][h] * rsqrtf(P.p[23][h] + 1e-5f);
        float s = 0.f;
        for (int c = 0; c < GCH; ++c) {
            float A1 = P.p[14][c] * rsqrtf(P.p[17][c] + 1e-5f);
            float C1 = (P.p[13][c] - P.p[16][c]) * A1 + P.p[15][c];
            s += C1 * P.p[18][(size_t)c * HID + h];
        }
        ws[OFF_BTG + h] = A2 * (s + P.p[19][h] - P.p[22][h]) + P.p[21][h];
    }
}

// conv inner: stream 12 b128 chunks of the 47-wide window with 1-deep
// lookahead; per-t FMA order is j (=t+k) ascending == k ascending:
// bit-identical to the scalar version.
__device__ __forceinline__ void conv_stream(const float4* __restrict__ xp4,
                                            const float* __restrict__ w,
                                            float* __restrict__ acc)
{
    float4 cur = xp4[0];
    #pragma unroll
    for (int j4 = 0; j4 < 12; ++j4) {
        float4 nxt = (j4 < 11) ? xp4[j4 + 1] : cur;
        #pragma unroll
        for (int i2 = 0; i2 < 4; ++i2) {
            const int i = j4 * 4 + i2;
            const float xv = (i2 == 0) ? cur.x : (i2 == 1) ? cur.y
                           : (i2 == 2) ? cur.z : cur.w;
            const int tlo = (i - 31 > 0) ? (i - 31) : 0;
            const int thi = (i < 15) ? i : 15;
            #pragma unroll
            for (int t = tlo; t <= thi; ++t)
                acc[t] = fmaf(xv, w[i - t], acc[t]);
        }
        cur = nxt;
    }
}

// ============================================================
// EEG path. Grid (NT, BSZ), block 256. 4 phases of 128 channels.
// xsT transposed [ch][j] stride 68 -> conv window via ds_read_b128 stream.
// dense: 4t x 4h, q = wave (4 chunks of 32 c/phase); software pipeline:
// wv (global, ~200cyc L2) prefetched 4-deep, cv (LDS, ~120cyc) 2-deep,
// modular SSA buffers (full unroll -> no v_movs). Stash-reduce at end.
// ============================================================
__global__ __launch_bounds__(256, 4)
void path_eeg(const float* __restrict__ x, float* __restrict__ ws)
{
    __shared__ __align__(16) float xsT[EEGC * 68];  // [ch][j], 17408 B
    __shared__ __align__(16) float czs[5120];       // cz[128*36] / stash[256*20]

    const int b   = blockIdx.y;
    const int t0  = blockIdx.x * TT;
    const int tid = threadIdx.x;
    const float* convW = ws + OFF_CWE;
    const float* dW    = ws + OFF_DWE;
    float* enc         = ws + OFF_ENC;
    float* cz          = czs;

    // stage x window transposed (zero-padded), coalesced global reads
    const float* xb = x + (size_t)b * (TLEN * EEGC);
    for (int i = tid; i < 63 * EEGC; i += 256) {
        int j = i >> 6, ch = i & 63;
        int t = t0 - 15 + j;
        xsT[ch * 68 + j] = (t >= 0 && t < TLEN) ? xb[(size_t)t * EEGC + ch] : 0.f;
    }
    __syncthreads();

    const int tg = tid & 7, hg = (tid >> 3) & 7, q = tid >> 6;
    const int c_loc = tid & 127, th = tid >> 7;
    float a00=0,a01=0,a02=0,a03=0, a10=0,a11=0,a12=0,a13=0;
    float a20=0,a21=0,a22=0,a23=0, a30=0,a31=0,a32=0,a33=0;

    #pragma unroll 1
    for (int ph = 0; ph < 4; ++ph) {
        if (ph) __syncthreads();   // previous dense reads done before cz overwrite
        // ---- conv: channel c = ph*128 + c_loc, t's [th*16, th*16+16) ----
        {
            const int c  = ph * 128 + c_loc;
            const int ch = c >> 3;
            float w[KW];
            const float4* wp4 = (const float4*)(convW + c * KW);
            #pragma unroll
            for (int k4 = 0; k4 < 8; ++k4) {
                float4 v = wp4[k4];
                w[4*k4+0]=v.x; w[4*k4+1]=v.y; w[4*k4+2]=v.z; w[4*k4+3]=v.w;
            }
            float acc[16];
            #pragma unroll
            for (int t = 0; t < 16; ++t) acc[t] = 0.f;
            conv_stream((const float4*)(xsT + ch * 68 + th * 16), w, acc);
            float4* czp = (float4*)(cz + c_loc * 36 + th * 16);
            czp[0] = make_float4(acc[0],  acc[1],  acc[2],  acc[3]);
            czp[1] = make_float4(acc[4],  acc[5],  acc[6],  acc[7]);
            czp[2] = make_float4(acc[8],  acc[9],  acc[10], acc[11]);
            czp[3] = make_float4(acc[12], acc[13], acc[14], acc[15]);
        }
        __syncthreads();
        // ---- dense partial: my wave's 32-c chunk, pipelined loads ----
        {
            const float* dWh = dW + (size_t)(ph * 128 + q * 32) * HID + hg * 4;
            const float* czb = cz + (q * 32) * 36 + tg * 4;
            float4 wvb[4], cvb[2];
            wvb[0] = *(const float4*)(dWh + 0 * HID);
            wvb[1] = *(const float4*)(dWh + 1 * HID);
            wvb[2] = *(const float4*)(dWh + 2 * HID);
            wvb[3] = *(const float4*)(dWh + 3 * HID);
            cvb[0] = *(const float4*)(czb + 0 * 36);
            cvb[1] = *(const float4*)(czb + 1 * 36);
            #pragma unroll
            for (int ci = 0; ci < 32; ++ci) {
                float4 cv = cvb[ci & 1];
                float4 wv = wvb[ci & 3];
                if (ci + 2 < 32) cvb[ci & 1] = *(const float4*)(czb + (ci + 2) * 36);
                if (ci + 4 < 32) wvb[ci & 3] = *(const float4*)(dWh + (ci + 4) * HID);
                a00 = fmaf(cv.x, wv.x, a00); a01 = fmaf(cv.x, wv.y, a01);
                a02 = fmaf(cv.x, wv.z, a02); a03 = fmaf(cv.x, wv.w, a03);
                a10 = fmaf(cv.y, wv.x, a10); a11 = fmaf(cv.y, wv.y, a11);
                a12 = fmaf(cv.y, wv.z, a12); a13 = fmaf(cv.y, wv.w, a13);
                a20 = fmaf(cv.z, wv.x, a20); a21 = fmaf(cv.z, wv.y, a21);
                a22 = fmaf(cv.z, wv.z, a22); a23 = fmaf(cv.z, wv.w, a23);
                a30 = fmaf(cv.w, wv.x, a30); a31 = fmaf(cv.w, wv.y, a31);
                a32 = fmaf(cv.w, wv.z, a32); a33 = fmaf(cv.w, wv.w, a33);
            }
        }
    }

    // ---- 4-chunk reduction via LDS (stash stride 20, b128) ----
    __syncthreads();
    float* stash = czs;   // 256*20 = 5120 floats
    {
        float4* sp = (float4*)(stash + tid * 20);
        sp[0] = make_float4(a00,a01,a02,a03);
        sp[1] = make_float4(a10,a11,a12,a13);
        sp[2] = make_float4(a20,a21,a22,a23);
        sp[3] = make_float4(a30,a31,a32,a33);
    }
    __syncthreads();
    {
        const int t = tid >> 3, hq = tid & 7;
        float4 v = make_float4(0.f,0.f,0.f,0.f);
        #pragma unroll
        for (int qq = 0; qq < 4; ++qq) {
            const int partner = qq * 64 + hq * 8 + (t >> 2);
            float4 s = *(const float4*)(stash + partner * 20 + (t & 3) * 4);
            v.x += s.x; v.y += s.y; v.z += s.z; v.w += s.w;
        }
        float4 bias = *(const float4*)(ws + OFF_BTE + hq * 4);
        v.x = fmaxf(v.x + bias.x, 0.f);
        v.y = fmaxf(v.y + bias.y, 0.f);
        v.z = fmaxf(v.z + bias.z, 0.f);
        v.w = fmaxf(v.w + bias.w, 0.f);
        *(float4*)(enc + ((size_t)(b * TLEN + t0 + t)) * HID + hq * 4) = v;
    }
}

// ============================================================
// GEO path: round-7 form (best measured): xs-staged scalar conv
// (tid<144, both th passes), dense 4 chunks of 36 c, sigmoid.
// LDS = 1134 + 5184 floats = 24.7 KB.
// ============================================================
__global__ __launch_bounds__(256, 4) void path_geo(const float* __restrict__ x,
                                                   float* __restrict__ ws)
{
    __shared__ __align__(16) float xs[63 * GEOC];   // 4536 B
    __shared__ __align__(16) float cz[GCH * 36];    // 20736 B (stash 5120 fits)

    const int b   = blockIdx.y;
    const int t0  = blockIdx.x * TT;
    const int tid = threadIdx.x;
    const float* convW = ws + OFF_CWG;
    const float* dW    = ws + OFF_DWG;
    float* mod         = ws + OFF_MOD;

    const float* xb = x + (size_t)b * (TLEN * GEOC);
    for (int i = tid; i < 63 * GEOC; i += 256) {
        int j = i / GEOC, ch = i - j * GEOC;
        int t = t0 - 15 + j;
        xs[i] = (t >= 0 && t < TLEN) ? xb[(size_t)t * GEOC + ch] : 0.f;
    }
    __syncthreads();

    if (tid < GCH) {
        const int c  = tid;
        const int ch = c >> 3;
        float w[KW];
        const float4* wp4 = (const float4*)(convW + c * KW);
        #pragma unroll
        for (int k4 = 0; k4 < 8; ++k4) {
            float4 v = wp4[k4];
            w[4*k4+0]=v.x; w[4*k4+1]=v.y; w[4*k4+2]=v.z; w[4*k4+3]=v.w;
        }
        #pragma unroll 1
        for (int th = 0; th < 2; ++th) {
            float xw[47];
            #pragma unroll
            for (int i = 0; i < 47; ++i) xw[i] = xs[(th*16 + i) * GEOC + ch];
            float acc[16];
            #pragma unroll
            for (int t = 0; t < 16; ++t) acc[t] = 0.f;
            #pragma unroll
            for (int k = 0; k < KW; ++k) {
                #pragma unroll
                for (int t = 0; t < 16; ++t)
                    acc[t] = fmaf(xw[t + k], w[k], acc[t]);
            }
            float4* czp = (float4*)(cz + tid * 36 + th * 16);
            czp[0] = make_float4(acc[0],  acc[1],  acc[2],  acc[3]);
            czp[1] = make_float4(acc[4],  acc[5],  acc[6],  acc[7]);
            czp[2] = make_float4(acc[8],  acc[9],  acc[10], acc[11]);
            czp[3] = make_float4(acc[12], acc[13], acc[14], acc[15]);
        }
    }
    __syncthreads();

    const int tg = tid & 7, hg = (tid >> 3) & 7, q = tid >> 6;
    float a00=0,a01=0,a02=0,a03=0, a10=0,a11=0,a12=0,a13=0;
    float a20=0,a21=0,a22=0,a23=0, a30=0,a31=0,a32=0,a33=0;
    {
        const float* dWh = dW + (size_t)(q * 36) * HID + hg * 4;
        const float* czb = cz + (q * 36) * 36 + tg * 4;
        #pragma unroll 2
        for (int ci = 0; ci < 36; ++ci) {
            float4 cv = *(const float4*)(czb + ci * 36);
            float4 wv = *(const float4*)(dWh + ci * HID);
            a00 = fmaf(cv.x, wv.x, a00); a01 = fmaf(cv.x, wv.y, a01);
            a02 = fmaf(cv.x, wv.z, a02); a03 = fmaf(cv.x, wv.w, a03);
            a10 = fmaf(cv.y, wv.x, a10); a11 = fmaf(cv.y, wv.y, a11);
            a12 = fmaf(cv.y, wv.z, a12); a13 = fmaf(cv.y, wv.w, a13);
            a20 = fmaf(cv.z, wv.x, a20); a21 = fmaf(cv.z, wv.y, a21);
            a22 = fmaf(cv.z, wv.z, a22); a23 = fmaf(cv.z, wv.w, a23);
            a30 = fmaf(cv.w, wv.x, a30); a31 = fmaf(cv.w, wv.y, a31);
            a32 = fmaf(cv.w, wv.z, a32); a33 = fmaf(cv.w, wv.w, a33);
        }
    }
    __syncthreads();
    float* stash = cz;
    {
        float4* sp = (float4*)(stash + tid * 20);
        sp[0] = make_float4(a00,a01,a02,a03);
        sp[1] = make_float4(a10,a11,a12,a13);
        sp[2] = make_float4(a20,a21,a22,a23);
        sp[3] = make_float4(a30,a31,a32,a33);
    }
    __syncthreads();
    {
        const int t = tid >> 3, hq = tid & 7;
        float4 v = make_float4(0.f,0.f,0.f,0.f);
        #pragma unroll
        for (int qq = 0; qq < 4; ++qq) {
            const int partner = qq * 64 + hq * 8 + (t >> 2);
            float4 s = *(const float4*)(stash + partner * 20 + (t & 3) * 4);
            v.x += s.x; v.y += s.y; v.z += s.z; v.w += s.w;
        }
        float4 bias = *(const float4*)(ws + OFF_BTG + hq * 4);
        v.x = 1.f / (1.f + expf(-(v.x + bias.x)));
        v.y = 1.f / (1.f + expf(-(v.y + bias.y)));
        v.z = 1.f / (1.f + expf(-(v.z + bias.z)));
        v.w = 1.f / (1.f + expf(-(v.w + bias.w)));
        *(float4*)(mod + ((size_t)(b * TLEN + t0 + t)) * HID + hq * 4) = v;
    }
}

// ============================================================
// SNN scan: one thread per (b,h). 320 serial steps; windowed mean-diff
// fused in-register. dp[b][h*10+w]
// ============================================================
__global__ __launch_bounds__(256) void scan_kernel(float* __restrict__ ws)
{
    const int idx = blockIdx.x * 256 + threadIdx.x;   // 0..32767
    const int b = idx >> 5, h = idx & 31;
    const float g = ws[OFF_GAM + h];
    const float* pe = ws + OFF_ENC + (size_t)b * TLEN * HID + h;
    const float* pg = ws + OFF_MOD + (size_t)b * TLEN * HID + h;
    float m1 = 0.f, m2 = 0.f, m3 = 0.f, ma = 0.f, eta = 0.f, mli = 0.f, prev = 0.f;
    float acc_lo = 0.f, acc_hi = 0.f;
    float* dpp = ws + OFF_DP + b * (HID * 10) + h * 10;
    int w = 0;
    #pragma unroll 8
    for (int t = 0; t < TLEN; ++t) {
        const float ce = pe[t * HID];
        const float cg = pg[t * HID];
        m1 = 0.9f * m1 + ce; float s1 = ((m1 - 0.7f) >= 0.f) ? 1.f : 0.f; m1 = m1 * (1.f - s1);
        m2 = 0.8f * m2 + ce; float s2 = ((m2 - 0.5f) >= 0.f) ? 1.f : 0.f; m2 = m2 * (1.f - s2);
        m3 = 0.6f * m3 + ce; float s3 = ((m3 - 0.3f) >= 0.f) ? 1.f : 0.f; m3 = m3 * (1.f - s3);
        const float hr = (s1 + s2 + s3) / 3.0f;
        eta = 0.36f * eta + 0.64f * prev;
        const float theta = 0.5f + 1.8f * eta - g * cg;
        ma = 0.8f * ma + hr;
        const float sa = ((ma - theta) >= 0.f) ? 1.f : 0.f;
        ma = ma * (1.f - sa);
        mli = 0.9f * mli + sa;
        prev = sa;
        if ((t & 31) < 16) acc_lo += mli; else acc_hi += mli;
        if ((t & 31) == 31) {
            dpp[w] = acc_hi * (1.f / 16.f) - acc_lo * (1.f / 16.f);
            acc_lo = 0.f; acc_hi = 0.f; ++w;
        }
    }
}

// ============================================================
// Head: fc1 (320->128) + ELU + fc2 (128->4). One block per b. f32 out.
// ============================================================
__global__ __launch_bounds__(128) void head_kernel(
    const float* __restrict__ ws,
    const float* __restrict__ f1w, const float* __restrict__ f1b,
    const float* __restrict__ f2w, const float* __restrict__ f2b,
    float* __restrict__ out)
{
    __shared__ float act[128];
    const int b = blockIdx.x, j = threadIdx.x;
    const float* dpb = ws + OFF_DP + b * 320;
    float a = f1b[j];
    for (int i = 0; i < 320; ++i)
        a = fmaf(dpb[i], f1w[i * 128 + j], a);
    act[j] = (a > 0.f) ? a : expm1f(a);   // ELU, alpha=1
    __syncthreads();
    if (j < 4) {
        float o = f2b[j];
        for (int jj = 0; jj < 128; ++jj)
            o = fmaf(act[jj], f2w[jj * 4 + j], o);
        out[b * 4 + j] = o;
    }
}

// ============================================================
extern "C" void kernel_launch(void* const* d_in, const int* in_sizes, int n_in,
                              void* d_out, int out_size, void* d_ws, size_t ws_size,
                              hipStream_t stream)
{
    float* ws = (float*)d_ws;

    P29 P;
    for (int k = 0; k < 29; ++k) P.p[k] = (const float*)d_in[k + 2];
    prep_kernel<<<1, 256, 0, stream>>>(P, ws);

    path_eeg<<<dim3(NT, BSZ), 256, 0, stream>>>((const float*)d_in[0], ws);
    path_geo<<<dim3(NT, BSZ), 256, 0, stream>>>((const float*)d_in[1], ws);

    scan_kernel<<<(BSZ * HID) / 256, 256, 0, stream>>>(ws);

    head_kernel<<<BSZ, 128, 0, stream>>>(
        ws, (const float*)d_in[27], (const float*)d_in[28],
        (const float*)d_in[29], (const float*)d_in[30], (float*)d_out);
}